// Round 1
// baseline (136.090 us; speedup 1.0000x reference)
//
#include <hip/hip_runtime.h>
#include <cfloat>

#define TPB 256
#define SCANT 1024
#define BKT 32768                 // buckets per side
#define EPT (BKT / SCANT)         // 32 buckets per scan-thread
#define RLO -8.0f                 // bucket range [-8, 8); clamped (exact for ANY data)
#define RSCALE (BKT / 16.0f)      // 2048 buckets per unit (exact power of two)
#define ALPHA 0.5f

// Order-preserving float <-> uint transform (monotone, total order on finite floats).
__device__ __forceinline__ unsigned enc_f(float v) {
    unsigned u = __float_as_uint(v);
    return (u & 0x80000000u) ? ~u : (u | 0x80000000u);
}
__device__ __forceinline__ float dec_f(unsigned e) {
    unsigned u = (e & 0x80000000u) ? (e & 0x7FFFFFFFu) : ~e;
    return __uint_as_float(u);
}
// Monotone non-decreasing in v (fl(v+8) monotone, *2048 exact, floor monotone).
// => bucket(y) < bucket(v) implies y < v; bucket(y) > bucket(v) implies y > v.
__device__ __forceinline__ int bucket_of(float v) {
    int b = (int)((v - RLO) * RSCALE);
    return min(max(b, 0), BKT - 1);
}

// Workspace layout (uint words):
//   0*BKT cnt_x      1*BKT cnt_y        (histogram)
//   2*BKT pmax_x     3*BKT pmax_y       (max enc per bucket -> prefix-max L)
//   4*BKT cmax_x     5*BKT cmax_y       (max ~enc per bucket -> suffix-"min" R)
//   6*BKT start_x    7*BKT start_y      (CSR bucket start)
//   8*BKT work_x     9*BKT work_y       (scatter cursor; == bucket end after scatter)
//  10*BKT sorted_x[n], sorted_y[m] (floats)
//  then (256B aligned) bsums: double[2*nb]
// Sentinel: enc/~enc of any finite float is > 0, so 0 == "bucket empty".

__global__ __launch_bounds__(TPB) void
chamfer_hist(const float* __restrict__ x, const float* __restrict__ y,
             int n, int m, unsigned* __restrict__ ws) {
    const int i = blockIdx.x * TPB + threadIdx.x;
    if (i >= n + m) return;
    const bool isx = i < n;
    const float v = isx ? x[i] : y[i - n];
    const int side = isx ? 0 : 1;
    const int b = bucket_of(v);
    const unsigned e = enc_f(v);
    atomicAdd(ws + 0 * BKT + side * BKT + b, 1u);
    atomicMax(ws + 2 * BKT + side * BKT + b, e);
    atomicMax(ws + 4 * BKT + side * BKT + b, ~e);
}

template <int OP>  // 0 = sum, 1 = max (identity 0 for both, values are unsigned)
__device__ __forceinline__ unsigned opf(unsigned a, unsigned b) {
    return OP == 0 ? (a + b) : (a > b ? a : b);
}

// Block-wide EXCLUSIVE scan over per-thread aggregates (1024 threads = 16 waves).
template <int OP>
__device__ unsigned blk_excl_scan(unsigned agg, unsigned* stmp) {
    const int lane = threadIdx.x & 63;
    const int w = threadIdx.x >> 6;
    unsigned incl = agg;
#pragma unroll
    for (int off = 1; off < 64; off <<= 1) {
        const unsigned u = __shfl_up(incl, off);
        if (lane >= off) incl = opf<OP>(incl, u);
    }
    unsigned ex = __shfl_up(incl, 1);
    if (lane == 0) ex = 0u;
    if (lane == 63) stmp[w] = incl;
    __syncthreads();
    if (threadIdx.x == 0) {  // serial over 16 wave aggregates: cheap
        unsigned run = 0u;
#pragma unroll
        for (int i = 0; i < SCANT / 64; ++i) {
            const unsigned v = stmp[i];
            stmp[i] = run;
            run = opf<OP>(run, v);
        }
    }
    __syncthreads();
    const unsigned r = opf<OP>(stmp[w], ex);
    __syncthreads();  // stmp reusable by next call
    return r;
}

// One block does all six scans: 2x prefix-sum (offsets), 2x prefix-max (L),
// 2x suffix-max of complement (R). 32768 elems, 32/thread.
__global__ __launch_bounds__(SCANT) void chamfer_scans(unsigned* __restrict__ ws) {
    __shared__ unsigned stmp[SCANT / 64];
    const int t = threadIdx.x;
#pragma unroll
    for (int side = 0; side < 2; ++side) {
        {   // exclusive prefix-sum: cnt -> start, work
            unsigned* cnt = ws + 0 * BKT + side * BKT;
            unsigned* start = ws + 6 * BKT + side * BKT;
            unsigned* work = ws + 8 * BKT + side * BKT;
            const int base = t * EPT;
            unsigned c[EPT], agg = 0;
#pragma unroll
            for (int i = 0; i < EPT; ++i) { c[i] = cnt[base + i]; agg += c[i]; }
            unsigned run = blk_excl_scan<0>(agg, stmp);
#pragma unroll
            for (int i = 0; i < EPT; ++i) {
                start[base + i] = run;
                work[base + i] = run;
                run += c[i];
            }
        }
        {   // inclusive prefix-max (in place): L[b] = max enc over buckets <= b
            unsigned* A = ws + 2 * BKT + side * BKT;
            const int base = t * EPT;
            unsigned a[EPT], agg = 0;
#pragma unroll
            for (int i = 0; i < EPT; ++i) { a[i] = A[base + i]; agg = opf<1>(agg, a[i]); }
            unsigned run = blk_excl_scan<1>(agg, stmp);
#pragma unroll
            for (int i = 0; i < EPT; ++i) { run = opf<1>(run, a[i]); A[base + i] = run; }
        }
        {   // inclusive suffix-max of ~enc (in place): R[b] ~ min enc over buckets >= b
            unsigned* A = ws + 4 * BKT + side * BKT;
            const int base = (SCANT - 1 - t) * EPT;   // reversed thread order
            unsigned a[EPT], agg = 0;
#pragma unroll
            for (int i = 0; i < EPT; ++i) { a[i] = A[base + i]; agg = opf<1>(agg, a[i]); }
            unsigned run = blk_excl_scan<1>(agg, stmp);
#pragma unroll
            for (int i = EPT - 1; i >= 0; --i) { run = opf<1>(run, a[i]); A[base + i] = run; }
        }
    }
}

__global__ __launch_bounds__(TPB) void
chamfer_scatter(const float* __restrict__ x, const float* __restrict__ y,
                int n, int m, unsigned* __restrict__ ws) {
    const int i = blockIdx.x * TPB + threadIdx.x;
    if (i >= n + m) return;
    const bool isx = i < n;
    const float v = isx ? x[i] : y[i - n];
    const int side = isx ? 0 : 1;
    const int b = bucket_of(v);
    const unsigned pos = atomicAdd(ws + 8 * BKT + side * BKT + b, 1u);
    float* sorted = (float*)(ws + 10 * BKT) + (isx ? 0 : n);
    sorted[pos] = v;   // order within bucket arbitrary: min over set is order-invariant
}

// Nearest neighbor is among: (a) own bucket's elements (CSR list),
// (b) max element of lower buckets (= dec(L[b-1])), (c) min element of higher
// buckets (= dec(~R[b+1])). Exact: bucket() is monotone, f32 |v - y| rounding
// is monotone in true distance, so min over this superset == min over all.
__global__ __launch_bounds__(TPB) void
chamfer_query(const float* __restrict__ x, const float* __restrict__ y,
              int n, int m, const unsigned* __restrict__ ws,
              double* __restrict__ bsums) {
    const int q = blockIdx.x * TPB + threadIdx.x;
    const int total = n + m;
    double sx = 0.0, sy = 0.0;
    if (q < total) {
        const bool isx = q < n;
        const float v = isx ? x[q] : y[q - n];
        const int side = isx ? 1 : 0;             // search the OTHER side's structure
        const unsigned* start = ws + 6 * BKT + side * BKT;
        const unsigned* endw  = ws + 8 * BKT + side * BKT;
        const unsigned* L     = ws + 2 * BKT + side * BKT;
        const unsigned* Rc    = ws + 4 * BKT + side * BKT;
        const float* sorted = (const float*)(ws + 10 * BKT) + (side ? n : 0);
        const int b = bucket_of(v);
        float best = FLT_MAX;
        const unsigned s0 = start[b], e0 = endw[b];
        for (unsigned i = s0; i < e0; ++i)
            best = fminf(best, fabsf(v - sorted[i]));
        if (b > 0) {
            const unsigned le = L[b - 1];
            if (le) best = fminf(best, fabsf(v - dec_f(le)));
        }
        if (b < BKT - 1) {
            const unsigned ce = Rc[b + 1];
            if (ce) best = fminf(best, fabsf(v - dec_f(~ce)));
        }
        if (isx) sx = (double)best; else sy = (double)best;
    }
    // deterministic block reduction (same structure as previous reduce1 tail)
    for (int off = 32; off > 0; off >>= 1) {
        sx += __shfl_down(sx, off);
        sy += __shfl_down(sy, off);
    }
    __shared__ double wsx[TPB / 64], wsy[TPB / 64];
    const int w = threadIdx.x >> 6;
    if ((threadIdx.x & 63) == 0) { wsx[w] = sx; wsy[w] = sy; }
    __syncthreads();
    if (threadIdx.x == 0) {
        double tx = 0.0, ty = 0.0;
#pragma unroll
        for (int i = 0; i < TPB / 64; ++i) { tx += wsx[i]; ty += wsy[i]; }
        bsums[2 * blockIdx.x] = tx;
        bsums[2 * blockIdx.x + 1] = ty;
    }
}

__global__ __launch_bounds__(TPB) void
chamfer_final(const double* __restrict__ bsums, int nb,
              int n, int m, float* __restrict__ out) {
    double sx = 0.0, sy = 0.0;
    for (int i = threadIdx.x; i < nb; i += blockDim.x) {
        sx += bsums[2 * i];
        sy += bsums[2 * i + 1];
    }
    for (int off = 32; off > 0; off >>= 1) {
        sx += __shfl_down(sx, off);
        sy += __shfl_down(sy, off);
    }
    __shared__ double lsx[4], lsy[4];
    const int wave = threadIdx.x >> 6;
    if ((threadIdx.x & 63) == 0) { lsx[wave] = sx; lsy[wave] = sy; }
    __syncthreads();
    if (threadIdx.x == 0) {
        double tx = 0.0, ty = 0.0;
        for (int w = 0; w < (int)(blockDim.x >> 6); ++w) { tx += lsx[w]; ty += lsy[w]; }
        const double a = (double)ALPHA;
        out[0] = (float)(a * tx / (double)n + (1.0 - a) * ty / (double)m);
    }
}

extern "C" void kernel_launch(void* const* d_in, const int* in_sizes, int n_in,
                              void* d_out, int out_size, void* d_ws, size_t ws_size,
                              hipStream_t stream) {
    const float* x = (const float*)d_in[0];
    const float* y = (const float*)d_in[1];
    const int n = in_sizes[0];
    const int m = in_sizes[1];
    float* out = (float*)d_out;
    const int total = n + m;

    unsigned* ws = (unsigned*)d_ws;
    const size_t meta_bytes = ((size_t)10 * BKT + (size_t)total) * sizeof(unsigned);
    const size_t meta_al = (meta_bytes + 255) & ~(size_t)255;
    double* bsums = (double*)((char*)d_ws + meta_al);

    const int nb = (total + TPB - 1) / TPB;   // 128 blocks for 32768 points

    // cnt/pmax/cmax zeroed in one fill (6*BKT words = 768 KB); 0 is the
    // identity/empty sentinel for all three. start/work/sorted fully rewritten.
    hipMemsetAsync(ws, 0, (size_t)6 * BKT * sizeof(unsigned), stream);
    chamfer_hist<<<nb, TPB, 0, stream>>>(x, y, n, m, ws);
    chamfer_scans<<<1, SCANT, 0, stream>>>(ws);
    chamfer_scatter<<<nb, TPB, 0, stream>>>(x, y, n, m, ws);
    chamfer_query<<<nb, TPB, 0, stream>>>(x, y, n, m, ws, bsums);
    chamfer_final<<<1, TPB, 0, stream>>>(bsums, nb, n, m, out);
}